// Round 1
// baseline (2221.679 us; speedup 1.0000x reference)
//
#include <hip/hip_runtime.h>
#include <math.h>

#define B 8
#define T 8192
#define D 20
#define H 8
#define G4 32   // 4*H

// ---------------------------------------------------------------------------
// Kernel 1: pre0[b,t,j] = sum_d x[b,t,d]*Wih0[j,d] + bih0[j] + bhh0[j]
// ---------------------------------------------------------------------------
__global__ __launch_bounds__(256) void pre0_kernel(
    const float* __restrict__ x, const float* __restrict__ Wih0,
    const float* __restrict__ bih0, const float* __restrict__ bhh0,
    float* __restrict__ pre0)
{
    __shared__ float sW[G4 * D];
    __shared__ float sB[G4];
    for (int i = threadIdx.x; i < G4 * D; i += 256) sW[i] = Wih0[i];
    if (threadIdx.x < G4) sB[threadIdx.x] = bih0[threadIdx.x] + bhh0[threadIdx.x];
    __syncthreads();

    int idx = blockIdx.x * 256 + threadIdx.x;   // idx = b*T + t
    if (idx >= B * T) return;

    float xv[D];
    const float4* xp = (const float4*)(x + (size_t)idx * D);  // 80B per thread, 16B aligned
    #pragma unroll
    for (int q = 0; q < D / 4; ++q) {
        float4 v = xp[q];
        xv[4*q+0] = v.x; xv[4*q+1] = v.y; xv[4*q+2] = v.z; xv[4*q+3] = v.w;
    }

    float outv[G4];
    #pragma unroll 4
    for (int j = 0; j < G4; ++j) {
        float acc = sB[j];
        #pragma unroll
        for (int k = 0; k < D; ++k) acc = fmaf(xv[k], sW[j*D + k], acc);
        outv[j] = acc;
    }
    float4* op = (float4*)(pre0 + (size_t)idx * G4);
    #pragma unroll
    for (int q = 0; q < G4 / 4; ++q)
        op[q] = make_float4(outv[4*q], outv[4*q+1], outv[4*q+2], outv[4*q+3]);
}

// ---------------------------------------------------------------------------
// Kernel 2: the sequential 2-layer scan. One block per batch, 32 active lanes
// (lane = gate index j; cell state for cell i lives on lane i, i<8).
// ---------------------------------------------------------------------------
__device__ __forceinline__ float bcast(float v, int srclane) {
    return __uint_as_float(__builtin_amdgcn_readlane(__float_as_uint(v), srclane));
}

__global__ __launch_bounds__(64) void scan_kernel(
    const float* __restrict__ pre0,
    const float* __restrict__ h0in, const float* __restrict__ c0in,
    const float* __restrict__ Whh0,
    const float* __restrict__ Wih1, const float* __restrict__ Whh1,
    const float* __restrict__ bih1, const float* __restrict__ bhh1,
    float* __restrict__ out)
{
    const int b = blockIdx.x;
    const int lane = threadIdx.x;
    if (lane >= G4) return;
    const int j = lane;           // gate index 0..31 ; gate class = j>>3 (i,f,g,o)
    const int gate = j >> 3;

    // per-lane weight rows
    float whh0[H], wih1[H], whh1[H];
    #pragma unroll
    for (int k = 0; k < H; ++k) {
        whh0[k] = Whh0[j*H + k];
        wih1[k] = Wih1[j*H + k];
        whh1[k] = Whh1[j*H + k];
    }
    const float bias1 = bih1[j] + bhh1[j];

    // states (valid on lanes 0..7; cell index == lane)
    float h0r = 0.f, c0r = 0.f, h1r = 0.f, c1r = 0.f;
    if (j < H) {
        h0r = h0in[0*B*H + b*H + j];
        c0r = c0in[0*B*H + b*H + j];
        h1r = h0in[1*B*H + b*H + j];
        c1r = c0in[1*B*H + b*H + j];
    }

    // branchless sigmoid/tanh selectors: gate 2 (g) uses tanh
    const float sc  = (gate == 2) ? 2.f : 1.f;
    const float m2  = (gate == 2) ? 2.f : 1.f;
    const float off = (gate == 2) ? -1.f : 0.f;

    const float* pp = pre0 + (size_t)b * T * G4;

    // distance-4 register prefetch pipeline
    float p[4];
    #pragma unroll
    for (int u = 0; u < 4; ++u) p[u] = pp[u*G4 + j];

    for (int t = 0; t < T; t += 4) {
        #pragma unroll
        for (int u = 0; u < 4; ++u) {
            float pc = p[u];
            int tn = t + 4 + u; if (tn > T - 1) tn = T - 1;
            p[u] = pp[(size_t)tn * G4 + j];

            // ---- layer 0 gate j
            float g = pc;
            #pragma unroll
            for (int k = 0; k < H; ++k) g = fmaf(bcast(h0r, k), whh0[k], g);
            float e   = __expf(-(sc * g));
            float act = fmaf(m2, __builtin_amdgcn_rcpf(1.f + e), off);
            // gather i,f,g,o for cell (lanes 0..7 meaningful)
            float fg = __shfl_xor(act, 8);
            float gg = __shfl_xor(act, 16);
            float og = __shfl_xor(act, 24);
            float cn = fmaf(fg, c0r, act * gg);
            float e2 = __expf(-2.f * cn);
            float hn = og * fmaf(2.f, __builtin_amdgcn_rcpf(1.f + e2), -1.f);
            c0r = (j < H) ? cn : c0r;
            h0r = (j < H) ? hn : h0r;

            // ---- layer 1 gate j  (input = new h0, recurrent = h1)
            float g1 = bias1;
            #pragma unroll
            for (int k = 0; k < H; ++k) g1 = fmaf(bcast(h0r, k), wih1[k], g1);
            #pragma unroll
            for (int k = 0; k < H; ++k) g1 = fmaf(bcast(h1r, k), whh1[k], g1);
            float e1 = __expf(-(sc * g1));
            float a1 = fmaf(m2, __builtin_amdgcn_rcpf(1.f + e1), off);
            float f1  = __shfl_xor(a1, 8);
            float gg1 = __shfl_xor(a1, 16);
            float o1  = __shfl_xor(a1, 24);
            float cn1 = fmaf(f1, c1r, a1 * gg1);
            float e3  = __expf(-2.f * cn1);
            float hn1 = o1 * fmaf(2.f, __builtin_amdgcn_rcpf(1.f + e3), -1.f);
            c1r = (j < H) ? cn1 : c1r;
            h1r = (j < H) ? hn1 : h1r;
        }
    }

    if (j < H) {
        // out layout: [0..1]=o2, [2..129]=hT[2,8,8], [130..257]=cT[2,8,8]
        out[2 +           0*B*H + b*H + j] = h0r;
        out[2 +           1*B*H + b*H + j] = h1r;
        out[2 + 2*B*H +   0*B*H + b*H + j] = c0r;
        out[2 + 2*B*H +   1*B*H + b*H + j] = c1r;
    }
}

// ---------------------------------------------------------------------------
// Kernel 3: head. o1_3[b] = bfc[3] + sum_k relu(hT1[b,k])*Wfc[3,k];
//           o2[m] = bi2h[m] + sum_b relu(o1_3[b])*Wi2h[m,b]
// ---------------------------------------------------------------------------
__global__ void head_kernel(const float* __restrict__ Wfc, const float* __restrict__ bfc,
                            const float* __restrict__ Wi2h, const float* __restrict__ bi2h,
                            float* __restrict__ out)
{
    if (threadIdx.x != 0 || blockIdx.x != 0) return;
    float o2a = bi2h[0], o2b = bi2h[1];
    for (int b = 0; b < B; ++b) {
        float s = bfc[3];
        for (int k = 0; k < H; ++k) {
            float h = out[2 + B*H + b*H + k];   // hT1
            h = h > 0.f ? h : 0.f;
            s = fmaf(h, Wfc[3*H + k], s);
        }
        s = s > 0.f ? s : 0.f;
        o2a = fmaf(s, Wi2h[0*B + b], o2a);
        o2b = fmaf(s, Wi2h[1*B + b], o2b);
    }
    out[0] = o2a;
    out[1] = o2b;
}

// ---------------------------------------------------------------------------
extern "C" void kernel_launch(void* const* d_in, const int* in_sizes, int n_in,
                              void* d_out, int out_size, void* d_ws, size_t ws_size,
                              hipStream_t stream)
{
    const float* x    = (const float*)d_in[0];
    const float* h0   = (const float*)d_in[1];
    const float* c0   = (const float*)d_in[2];
    const float* Wih0 = (const float*)d_in[3];
    const float* Whh0 = (const float*)d_in[4];
    const float* bih0 = (const float*)d_in[5];
    const float* bhh0 = (const float*)d_in[6];
    const float* Wih1 = (const float*)d_in[7];
    const float* Whh1 = (const float*)d_in[8];
    const float* bih1 = (const float*)d_in[9];
    const float* bhh1 = (const float*)d_in[10];
    const float* Wfc  = (const float*)d_in[11];
    const float* bfc  = (const float*)d_in[12];
    const float* Wi2h = (const float*)d_in[13];
    const float* bi2h = (const float*)d_in[14];
    float* out  = (float*)d_out;
    float* pre0 = (float*)d_ws;   // needs B*T*32*4 = 8.4 MB of scratch

    pre0_kernel<<<(B*T + 255) / 256, 256, 0, stream>>>(x, Wih0, bih0, bhh0, pre0);
    scan_kernel<<<B, 64, 0, stream>>>(pre0, h0, c0, Whh0, Wih1, Whh1, bih1, bhh1, out);
    head_kernel<<<1, 64, 0, stream>>>(Wfc, bfc, Wi2h, bi2h, out);
}

// Round 2
// 1870.757 us; speedup vs baseline: 1.1876x; 1.1876x over previous
//
#include <hip/hip_runtime.h>
#include <math.h>

#define B 8
#define T 8192
#define D 20
#define H 8
#define G4 32   // 4*H
#define LOG2E 1.4426950408889634f

// ---------------------------------------------------------------------------
// helpers
// ---------------------------------------------------------------------------
__device__ __forceinline__ float bcastf(float v, int srclane) {
    return __uint_as_float(__builtin_amdgcn_readlane(__float_as_uint(v), srclane));
}
// broadcast lane q of each quad to the whole quad (VALU DPP, no LDS)
template<int q>
__device__ __forceinline__ float qbcast(float v) {
    return __uint_as_float((unsigned)__builtin_amdgcn_update_dpp(
        0, (int)__float_as_uint(v), q * 0x55, 0xF, 0xF, true));
}

// ---------------------------------------------------------------------------
// Kernel 1: pre0p[b,t,lane] with lane = cell*4 + gateclass, value =
//   alpha(gate) * (x·Wih0[j] + bih0[j] + bhh0[j]),  j = gateclass*8 + cell
// alpha = -log2e (sigmoid gates) or -2log2e (g gate) so the scan kernel can
// use v_exp_f32 (exp2) directly.
// ---------------------------------------------------------------------------
__global__ __launch_bounds__(256) void pre0_kernel(
    const float* __restrict__ x, const float* __restrict__ Wih0,
    const float* __restrict__ bih0, const float* __restrict__ bhh0,
    float* __restrict__ pre0p)
{
    __shared__ float sW[G4 * D];
    __shared__ float sB[G4];
    for (int i = threadIdx.x; i < G4 * D; i += 256) sW[i] = Wih0[i];
    if (threadIdx.x < G4) sB[threadIdx.x] = bih0[threadIdx.x] + bhh0[threadIdx.x];
    __syncthreads();

    int idx = blockIdx.x * 256 + threadIdx.x;   // idx = b*T + t
    if (idx >= B * T) return;

    float xv[D];
    const float4* xp = (const float4*)(x + (size_t)idx * D);
    #pragma unroll
    for (int qq = 0; qq < D / 4; ++qq) {
        float4 v = xp[qq];
        xv[4*qq+0] = v.x; xv[4*qq+1] = v.y; xv[4*qq+2] = v.z; xv[4*qq+3] = v.w;
    }

    float outv[G4];
    #pragma unroll 4
    for (int j = 0; j < G4; ++j) {
        float acc = sB[j];
        #pragma unroll
        for (int k = 0; k < D; ++k) acc = fmaf(xv[k], sW[j*D + k], acc);
        outv[j] = acc;
    }

    const float as = -LOG2E, at = -2.f * LOG2E;
    float4* op = (float4*)(pre0p + (size_t)idx * G4);
    #pragma unroll
    for (int c = 0; c < H; ++c)   // position c*4+q  <-  gate j=q*8+c
        op[c] = make_float4(as*outv[c], as*outv[8+c], at*outv[16+c], as*outv[24+c]);
}

// ---------------------------------------------------------------------------
// Kernel 2: sequential 2-layer scan. One block per batch, 32 active lanes.
// lane = cell*4 + gateclass; gates of a cell gathered via quad_perm DPP.
// Zero DS ops; broadcasts via v_readlane (SGPR).
// ---------------------------------------------------------------------------
__global__ __launch_bounds__(64) void scan_kernel(
    const float* __restrict__ pre0p,
    const float* __restrict__ h0in, const float* __restrict__ c0in,
    const float* __restrict__ Whh0,
    const float* __restrict__ Wih1, const float* __restrict__ Whh1,
    const float* __restrict__ bih1, const float* __restrict__ bhh1,
    float* __restrict__ out)
{
    const int b = blockIdx.x;
    const int lane = threadIdx.x;
    if (lane >= G4) return;
    const int c = lane >> 2;      // cell 0..7
    const int q = lane & 3;       // gate class: 0=i 1=f 2=g 3=o
    const int j = q * H + c;      // original gate row

    const float alpha = (q == 2) ? (-2.f * LOG2E) : (-LOG2E);
    const float m2    = (q == 2) ? 2.f : 1.f;
    const float off   = (q == 2) ? -1.f : 0.f;
    const float TK    = -2.f * LOG2E;   // tanh(c) argument scale

    float whh0[H], wih1[H], whh1[H];
    #pragma unroll
    for (int k = 0; k < H; ++k) {
        whh0[k] = alpha * Whh0[j*H + k];
        wih1[k] = alpha * Wih1[j*H + k];
        whh1[k] = alpha * Whh1[j*H + k];
    }
    const float bias1 = alpha * (bih1[j] + bhh1[j]);

    // per-lane cell state (uniform within each quad)
    float h0 = h0in[0*B*H + b*H + c];
    float c0 = c0in[0*B*H + b*H + c];
    float h1 = h0in[1*B*H + b*H + c];
    float c1 = c0in[1*B*H + b*H + c];

    float sh0[H], sh1[H];
    #pragma unroll
    for (int k = 0; k < H; ++k) { sh0[k] = bcastf(h0, 4*k); sh1[k] = bcastf(h1, 4*k); }

    const float* pp = pre0p + (size_t)b * T * G4 + lane;

    #define UNR 8
    float p[UNR];
    #pragma unroll
    for (int u = 0; u < UNR; ++u) p[u] = pp[(size_t)u * G4];

    for (int t = 0; t < T; t += UNR) {
        #pragma unroll
        for (int u = 0; u < UNR; ++u) {
            float pc = p[u];
            int tn = t + UNR + u; if (tn > T - 1) tn = T - 1;
            p[u] = pp[(size_t)tn * G4];

            // ---- layer1 recurrent partial (off-chain: stale sh1)
            float a1 = bias1, b1 = 0.f;
            #pragma unroll
            for (int k = 0; k < 4; ++k) a1 = fmaf(sh1[k], whh1[k], a1);
            #pragma unroll
            for (int k = 4; k < H; ++k) b1 = fmaf(sh1[k], whh1[k], b1);

            // ---- layer0 gate (chain head)
            float a0 = pc, b0 = 0.f;
            #pragma unroll
            for (int k = 0; k < 4; ++k) a0 = fmaf(sh0[k], whh0[k], a0);
            #pragma unroll
            for (int k = 4; k < H; ++k) b0 = fmaf(sh0[k], whh0[k], b0);
            float e0   = exp2f(a0 + b0);                    // arg pre-scaled
            float r0   = __builtin_amdgcn_rcpf(1.f + e0);
            float act0 = fmaf(m2, r0, off);                 // sigmoid or tanh
            float iv = qbcast<0>(act0);
            float fv = qbcast<1>(act0);
            float gv = qbcast<2>(act0);
            float ov = qbcast<3>(act0);
            float cn = fmaf(fv, c0, iv * gv);
            float e2 = exp2f(TK * cn);
            float r2 = __builtin_amdgcn_rcpf(1.f + e2);
            float hn = ov * fmaf(2.f, r2, -1.f);            // o * tanh(c)
            c0 = cn; h0 = hn;
            #pragma unroll
            for (int k = 0; k < H; ++k) sh0[k] = bcastf(h0, 4*k);

            // ---- layer1 completes with fresh h0
            #pragma unroll
            for (int k = 0; k < 4; ++k) a1 = fmaf(sh0[k], wih1[k], a1);
            #pragma unroll
            for (int k = 4; k < H; ++k) b1 = fmaf(sh0[k], wih1[k], b1);
            float e1   = exp2f(a1 + b1);
            float r1   = __builtin_amdgcn_rcpf(1.f + e1);
            float act1 = fmaf(m2, r1, off);
            float iv1 = qbcast<0>(act1);
            float fv1 = qbcast<1>(act1);
            float gv1 = qbcast<2>(act1);
            float ov1 = qbcast<3>(act1);
            float cn1 = fmaf(fv1, c1, iv1 * gv1);
            float e3  = exp2f(TK * cn1);
            float r3  = __builtin_amdgcn_rcpf(1.f + e3);
            float hn1 = ov1 * fmaf(2.f, r3, -1.f);
            c1 = cn1; h1 = hn1;
            #pragma unroll
            for (int k = 0; k < H; ++k) sh1[k] = bcastf(h1, 4*k);
        }
    }

    if (q == 0) {
        // out layout: [0..1]=o2, [2..129]=hT[2,8,8], [130..257]=cT[2,8,8]
        out[2 +         0*B*H + b*H + c] = h0;
        out[2 +         1*B*H + b*H + c] = h1;
        out[2 + 2*B*H + 0*B*H + b*H + c] = c0;
        out[2 + 2*B*H + 1*B*H + b*H + c] = c1;
    }
}

// ---------------------------------------------------------------------------
// Kernel 3: head (unchanged)
// ---------------------------------------------------------------------------
__global__ void head_kernel(const float* __restrict__ Wfc, const float* __restrict__ bfc,
                            const float* __restrict__ Wi2h, const float* __restrict__ bi2h,
                            float* __restrict__ out)
{
    if (threadIdx.x != 0 || blockIdx.x != 0) return;
    float o2a = bi2h[0], o2b = bi2h[1];
    for (int b = 0; b < B; ++b) {
        float s = bfc[3];
        for (int k = 0; k < H; ++k) {
            float h = out[2 + B*H + b*H + k];   // hT1
            h = h > 0.f ? h : 0.f;
            s = fmaf(h, Wfc[3*H + k], s);
        }
        s = s > 0.f ? s : 0.f;
        o2a = fmaf(s, Wi2h[0*B + b], o2a);
        o2b = fmaf(s, Wi2h[1*B + b], o2b);
    }
    out[0] = o2a;
    out[1] = o2b;
}

// ---------------------------------------------------------------------------
extern "C" void kernel_launch(void* const* d_in, const int* in_sizes, int n_in,
                              void* d_out, int out_size, void* d_ws, size_t ws_size,
                              hipStream_t stream)
{
    const float* x    = (const float*)d_in[0];
    const float* h0   = (const float*)d_in[1];
    const float* c0   = (const float*)d_in[2];
    const float* Wih0 = (const float*)d_in[3];
    const float* Whh0 = (const float*)d_in[4];
    const float* bih0 = (const float*)d_in[5];
    const float* bhh0 = (const float*)d_in[6];
    const float* Wih1 = (const float*)d_in[7];
    const float* Whh1 = (const float*)d_in[8];
    const float* bih1 = (const float*)d_in[9];
    const float* bhh1 = (const float*)d_in[10];
    const float* Wfc  = (const float*)d_in[11];
    const float* bfc  = (const float*)d_in[12];
    const float* Wi2h = (const float*)d_in[13];
    const float* bi2h = (const float*)d_in[14];
    float* out   = (float*)d_out;
    float* pre0p = (float*)d_ws;   // B*T*32*4 = 8.4 MB scratch

    pre0_kernel<<<(B*T + 255) / 256, 256, 0, stream>>>(x, Wih0, bih0, bhh0, pre0p);
    scan_kernel<<<B, 64, 0, stream>>>(pre0p, h0, c0, Whh0, Wih1, Whh1, bih1, bhh1, out);
    head_kernel<<<1, 64, 0, stream>>>(Wfc, bfc, Wi2h, bi2h, out);
}

// Round 3
// 1047.704 us; speedup vs baseline: 2.1205x; 1.7856x over previous
//
#include <hip/hip_runtime.h>
#include <math.h>

#define B 8
#define T 8192
#define D 20
#define H 8
#define G4 32   // 4*H
#define LOG2E 1.4426950408889634f
#define UNR 8

// ---------------------------------------------------------------------------
// helpers
// ---------------------------------------------------------------------------
__device__ __forceinline__ float bcastf(float v, int srclane) {
    return __uint_as_float(__builtin_amdgcn_readlane(__float_as_uint(v), srclane));
}
// broadcast lane q of each quad to the whole quad (VALU DPP, no LDS)
template<int q>
__device__ __forceinline__ float qbcast(float v) {
    return __uint_as_float((unsigned)__builtin_amdgcn_update_dpp(
        0, (int)__float_as_uint(v), q * 0x55, 0xF, 0xF, true));
}

// ---------------------------------------------------------------------------
// Kernel 1: pre0p[b,t,lane32] with lane32 = cell*4 + gateclass, value =
//   alpha(gate) * (x·Wih0[j] + bih0[j] + bhh0[j]),  j = gateclass*8 + cell
// alpha = -log2e (sigmoid) or -2log2e (g gate) so scan uses v_exp_f32 directly.
// ---------------------------------------------------------------------------
__global__ __launch_bounds__(256) void pre0_kernel(
    const float* __restrict__ x, const float* __restrict__ Wih0,
    const float* __restrict__ bih0, const float* __restrict__ bhh0,
    float* __restrict__ pre0p)
{
    __shared__ float sW[G4 * D];
    __shared__ float sB[G4];
    for (int i = threadIdx.x; i < G4 * D; i += 256) sW[i] = Wih0[i];
    if (threadIdx.x < G4) sB[threadIdx.x] = bih0[threadIdx.x] + bhh0[threadIdx.x];
    __syncthreads();

    int idx = blockIdx.x * 256 + threadIdx.x;   // idx = b*T + t
    if (idx >= B * T) return;

    float xv[D];
    const float4* xp = (const float4*)(x + (size_t)idx * D);
    #pragma unroll
    for (int qq = 0; qq < D / 4; ++qq) {
        float4 v = xp[qq];
        xv[4*qq+0] = v.x; xv[4*qq+1] = v.y; xv[4*qq+2] = v.z; xv[4*qq+3] = v.w;
    }

    float outv[G4];
    #pragma unroll 4
    for (int j = 0; j < G4; ++j) {
        float acc = sB[j];
        #pragma unroll
        for (int k = 0; k < D; ++k) acc = fmaf(xv[k], sW[j*D + k], acc);
        outv[j] = acc;
    }

    const float as = -LOG2E, at = -2.f * LOG2E;
    float4* op = (float4*)(pre0p + (size_t)idx * G4);
    #pragma unroll
    for (int c = 0; c < H; ++c)   // position c*4+q  <-  gate j=q*8+c
        op[c] = make_float4(as*outv[c], as*outv[8+c], at*outv[16+c], as*outv[24+c]);
}

// ---------------------------------------------------------------------------
// Kernel 2: dual-layer pipelined scan. One block per batch, 64 lanes:
//   lanes 0-31  : layer0 step i      (lane = cell*4 + gateclass)
//   lanes 32-63 : layer1 step i-1    (same sub-layout)
// Shared broadcasts: sv[0..7]=h0[i-1] (used by BOTH halves), sv[8..15]=h1[i-2].
// One exp/rcp/dpp/tanh pipeline serves both layers per iteration.
// ---------------------------------------------------------------------------
__global__ __launch_bounds__(64) void scan_kernel(
    const float* __restrict__ pre0p,
    const float* __restrict__ h0in, const float* __restrict__ c0in,
    const float* __restrict__ Whh0,
    const float* __restrict__ Wih1, const float* __restrict__ Whh1,
    const float* __restrict__ bih1, const float* __restrict__ bhh1,
    float* __restrict__ out)
{
    const int b = blockIdx.x;
    const int lane = threadIdx.x;
    const int half = lane >> 5;       // 0 = layer0, 1 = layer1
    const int c = (lane >> 2) & 7;    // cell
    const int q = lane & 3;           // gate class: 0=i 1=f 2=g 3=o
    const int j = q * H + c;

    const float alpha = (q == 2) ? (-2.f * LOG2E) : (-LOG2E);
    const float m2    = (q == 2) ? 2.f : 1.f;
    const float off   = (q == 2) ? -1.f : 0.f;
    const float TK    = -2.f * LOG2E;

    // merged weight row: lower half = [Whh0 | 0], upper half = [Wih1 | Whh1]
    float w[16];
    #pragma unroll
    for (int k = 0; k < H; ++k) {
        if (half == 0) { w[k] = alpha * Whh0[j*H + k]; w[8+k] = 0.f; }
        else           { w[k] = alpha * Wih1[j*H + k]; w[8+k] = alpha * Whh1[j*H + k]; }
    }
    const float bias1 = alpha * (bih1[j] + bhh1[j]);   // only consumed on upper half

    const int sidx = half * B * H + b * H + c;
    float cv    = c0in[sidx];       // per-lane cell state (own layer)
    float cinit = cv;
    float hinit = h0in[sidx];

    float sv[16];
    #pragma unroll
    for (int k = 0; k < H; ++k) {
        sv[k]     = bcastf(hinit, 4*k);        // h0 state
        sv[8 + k] = bcastf(hinit, 32 + 4*k);   // h1 state
    }

    const float* pp = pre0p + (size_t)b * T * G4 + (lane & 31);

    // distance-UNR prefetch for iterations 1..UNR
    float p[UNR];
    #pragma unroll
    for (int u = 0; u < UNR; ++u) p[u] = pp[(size_t)(1 + u) * G4];
    float pc0 = pp[0];

    float hn = hinit;

#define BODY(PC)                                                          \
    {                                                                     \
        float a0 = (half == 0) ? (PC) : bias1;                            \
        float a1 = 0.f, a2 = 0.f, a3 = 0.f;                               \
        a0 = fmaf(sv[0],  w[0],  a0);  a1 = fmaf(sv[1],  w[1],  a1);      \
        a2 = fmaf(sv[2],  w[2],  a2);  a3 = fmaf(sv[3],  w[3],  a3);      \
        a0 = fmaf(sv[4],  w[4],  a0);  a1 = fmaf(sv[5],  w[5],  a1);      \
        a2 = fmaf(sv[6],  w[6],  a2);  a3 = fmaf(sv[7],  w[7],  a3);      \
        a0 = fmaf(sv[8],  w[8],  a0);  a1 = fmaf(sv[9],  w[9],  a1);      \
        a2 = fmaf(sv[10], w[10], a2);  a3 = fmaf(sv[11], w[11], a3);      \
        a0 = fmaf(sv[12], w[12], a0);  a1 = fmaf(sv[13], w[13], a1);      \
        a2 = fmaf(sv[14], w[14], a2);  a3 = fmaf(sv[15], w[15], a3);      \
        float g  = (a0 + a1) + (a2 + a3);                                 \
        float e  = exp2f(g);                                              \
        float r  = __builtin_amdgcn_rcpf(1.f + e);                        \
        float act = fmaf(m2, r, off);                                     \
        float iv = qbcast<0>(act);                                        \
        float fv = qbcast<1>(act);                                        \
        float gv = qbcast<2>(act);                                        \
        float ov = qbcast<3>(act);                                        \
        float cn = fmaf(fv, cv, iv * gv);                                 \
        float e2 = exp2f(TK * cn);                                        \
        float r2 = __builtin_amdgcn_rcpf(1.f + e2);                       \
        hn = ov * fmaf(2.f, r2, -1.f);                                    \
        cv = cn;                                                          \
        sv[0]  = bcastf(hn, 0);   sv[1]  = bcastf(hn, 4);                 \
        sv[2]  = bcastf(hn, 8);   sv[3]  = bcastf(hn, 12);                \
        sv[4]  = bcastf(hn, 16);  sv[5]  = bcastf(hn, 20);                \
        sv[6]  = bcastf(hn, 24);  sv[7]  = bcastf(hn, 28);                \
        sv[8]  = bcastf(hn, 32);  sv[9]  = bcastf(hn, 36);                \
        sv[10] = bcastf(hn, 40);  sv[11] = bcastf(hn, 44);                \
        sv[12] = bcastf(hn, 48);  sv[13] = bcastf(hn, 52);                \
        sv[14] = bcastf(hn, 56);  sv[15] = bcastf(hn, 60);                \
    }

    // ---- peel iteration 0: L0 step 0 only; restore L1 half's state after
    BODY(pc0);
    cv = (half == 0) ? cv : cinit;                  // L1 state untouched
    #pragma unroll
    for (int k = 0; k < H; ++k) sv[8 + k] = bcastf(hinit, 32 + 4*k);

    // ---- main loop: iterations i = 1 .. 8184  (1023 blocks of UNR=8)
    for (int i0 = 1; i0 <= T - UNR; i0 += UNR) {
        #pragma unroll
        for (int u = 0; u < UNR; ++u) {
            float pcur = p[u];
            int tn = i0 + u + UNR; if (tn > T - 1) tn = T - 1;
            p[u] = pp[(size_t)tn * G4];
            BODY(pcur);
        }
    }

    // ---- tail: iterations i = 8185 .. 8191 (7), pre-values in p[0..6]
    #pragma unroll
    for (int u = 0; u < 7; ++u) BODY(p[u]);

    float h0_final = hn;   // lower half: h0[T-1]
    float c0_final = cv;

    // ---- epilogue: L1 step T-1 (lower half computes discarded garbage)
    BODY(p[6]);

    if (q == 0) {
        // out layout: [0..1]=o2, [2..129]=hT[2,8,8], [130..257]=cT[2,8,8]
        if (half == 0) {
            out[2 +           b*H + c] = h0_final;
            out[2 + 2*B*H +   b*H + c] = c0_final;
        } else {
            out[2 +   B*H +   b*H + c] = hn;    // h1[T-1]
            out[2 + 3*B*H +   b*H + c] = cv;    // c1[T-1]
        }
    }
#undef BODY
}

// ---------------------------------------------------------------------------
// Kernel 3: head (unchanged)
// ---------------------------------------------------------------------------
__global__ void head_kernel(const float* __restrict__ Wfc, const float* __restrict__ bfc,
                            const float* __restrict__ Wi2h, const float* __restrict__ bi2h,
                            float* __restrict__ out)
{
    if (threadIdx.x != 0 || blockIdx.x != 0) return;
    float o2a = bi2h[0], o2b = bi2h[1];
    for (int b = 0; b < B; ++b) {
        float s = bfc[3];
        for (int k = 0; k < H; ++k) {
            float h = out[2 + B*H + b*H + k];   // hT1
            h = h > 0.f ? h : 0.f;
            s = fmaf(h, Wfc[3*H + k], s);
        }
        s = s > 0.f ? s : 0.f;
        o2a = fmaf(s, Wi2h[0*B + b], o2a);
        o2b = fmaf(s, Wi2h[1*B + b], o2b);
    }
    out[0] = o2a;
    out[1] = o2b;
}

// ---------------------------------------------------------------------------
extern "C" void kernel_launch(void* const* d_in, const int* in_sizes, int n_in,
                              void* d_out, int out_size, void* d_ws, size_t ws_size,
                              hipStream_t stream)
{
    const float* x    = (const float*)d_in[0];
    const float* h0   = (const float*)d_in[1];
    const float* c0   = (const float*)d_in[2];
    const float* Wih0 = (const float*)d_in[3];
    const float* Whh0 = (const float*)d_in[4];
    const float* bih0 = (const float*)d_in[5];
    const float* bhh0 = (const float*)d_in[6];
    const float* Wih1 = (const float*)d_in[7];
    const float* Whh1 = (const float*)d_in[8];
    const float* bih1 = (const float*)d_in[9];
    const float* bhh1 = (const float*)d_in[10];
    const float* Wfc  = (const float*)d_in[11];
    const float* bfc  = (const float*)d_in[12];
    const float* Wi2h = (const float*)d_in[13];
    const float* bi2h = (const float*)d_in[14];
    float* out   = (float*)d_out;
    float* pre0p = (float*)d_ws;   // B*T*32*4 = 8.4 MB scratch

    pre0_kernel<<<(B*T + 255) / 256, 256, 0, stream>>>(x, Wih0, bih0, bhh0, pre0p);
    scan_kernel<<<B, 64, 0, stream>>>(pre0p, h0, c0, Whh0, Wih1, Whh1, bih1, bhh1, out);
    head_kernel<<<1, 64, 0, stream>>>(Wfc, bfc, Wi2h, bi2h, out);
}